// Round 8
// baseline (134.316 us; speedup 1.0000x reference)
//
#include <hip/hip_runtime.h>
#include <math.h>

#define BATCH   8192
#define NOUTER  50
#define NINNER  15
#define NTHREADS (BATCH * 8)   // 8 lanes per element: net(2) x branch(4)

__device__ __forceinline__ float fast_rcp(float x)  { return __builtin_amdgcn_rcpf(x); }
__device__ __forceinline__ float fast_sqrt(float x) { return __builtin_amdgcn_sqrtf(x); }

// DPP cross-lane move (VALU pipe). quad_perm = sel0|sel1<<2|sel2<<4|sel3<<6
template <int CTRL>
__device__ __forceinline__ float dpp_movf(float x) {
    return __int_as_float(__builtin_amdgcn_update_dpp(
        0, __float_as_int(x), CTRL, 0xF, 0xF, true));
}
#define DPP_XOR1  0xB1   // quad_perm [1,0,3,2]
#define DPP_XOR2  0x4E   // quad_perm [2,3,0,1]
#define DPP_BQ0   0x00   // quad_perm [0,0,0,0] : broadcast quad lane 0
#define DPP_ROR8  0x128  // row_ror:8  == xor8 within 16-lane row (on 8-uniform data)
#define DPP_HMIR  0x141  // row_half_mirror == xor7 (== xor4 on quad-uniform data)

// ---------------------------------------------------------------------------
// Lane-parallel flow distribution. Each lane owns ONE branch. Cross-branch
// sums via quad_perm DPP. Bit-identical math to rounds 2-6.
// ---------------------------------------------------------------------------
__device__ __forceinline__ float distribute_lane(float total, float R2, float Rl,
                                                 float& pout) {
    float f = total * 0.25f;
#pragma unroll
    for (int it = 0; it < NINNER; ++it) {
        float p  = fmaf(R2, f * f, Rl * f);          // f >= 0 -> |f| == f
        float t  = p + dpp_movf<DPP_XOR1>(p);
        t       += dpp_movf<DPP_XOR2>(t);
        float target = t * 0.25f;
        float q2e = fmaf(f, f, 1e-6f);
        float den = fmaf(q2e, 1e-6f, p);
        float ratio = target * q2e * fast_rcp(den);  // >= 0 by construction
        float nw = fast_sqrt(ratio);
        float s  = nw + dpp_movf<DPP_XOR1>(nw);
        s       += dpp_movf<DPP_XOR2>(s);
        f = nw * total * fast_rcp(s + 1e-6f);
    }
    pout = fmaf(R2, f * f, Rl * f);
    return f;
}

__device__ __forceinline__ float fan_pressure(float flow, float rspeed, float speed2,
                                              float a1000, float b, float c) {
    float fn = flow * rspeed;
    float pd = fmaf(c, fn * fn, fmaf(b, fn, a1000));
    return fmaxf(pd * speed2, 0.0f);
}

// sys pressure = p0(sup) + p0(exh), broadcast to all 8 lanes of the element.
__device__ __forceinline__ float sys_from_p(float pfin) {
    float p0 = dpp_movf<DPP_BQ0>(pfin);
    return p0 + dpp_movf<DPP_HMIR>(p0);
}

struct LaneConsts {
    float R2, Rl;
    float speed, rspeed, speed2, a1000, b, c;
    int elem, lane, sub;
};

__device__ __forceinline__ LaneConsts setup_lane(
        const float* fan_speed,
        const float* sup_pos, const float* exh_pos,
        const float* pa, const float* pb, const float* pc,
        const float* slr, const float* srl, const float* sdo, const float* sdk,
        const float* elr, const float* erl, const float* edo, const float* edk) {
    LaneConsts L;
    int t   = blockIdx.x * blockDim.x + threadIdx.x;
    L.elem  = t >> 3;
    L.sub   = t & 7;
    int net = (L.sub >> 2) & 1;
    int j   = L.sub & 3;
    L.lane  = threadIdx.x & 63;

    const float* pos = net ? exh_pos : sup_pos;
    const float* lr  = net ? elr : slr;
    const float* rl  = net ? erl : srl;
    const float* dlo = net ? edo : sdo;
    const float* dk  = net ? edk : sdk;

    float Rduct = expf(lr[j]);
    float Rd    = expf(dlo[j]) * expf(dk[j] * (1.0f - pos[L.elem * 4 + j]));
    L.R2 = Rduct + Rd;
    L.Rl = fabsf(rl[j]);

    L.speed  = fan_speed[L.elem];
    L.rspeed = fast_rcp(L.speed + 1e-6f);
    L.speed2 = L.speed * L.speed;
    L.a1000  = pa[0] * 1000.0f;
    L.b      = pb[0];
    L.c      = pc[0];
    return L;
}

// ---------------------------------------------------------------------------
// Phase 1: all 50 outer iterations ungated. Hot loop contains NO atomics, NO
// DS ops, NO reduce ops (in-order single-wave issue: every extra dependent op
// stalls — round-5 lesson). sub==0 lanes store the element-uniform |res| to
// stage (8 consecutive floats per wave = one 32B transaction, off-chain).
// Fallback (stage==nullptr): wave reduce + atomicMax.
// ---------------------------------------------------------------------------
__global__ __launch_bounds__(256) void phase1(
        const float* __restrict__ fan_speed,
        const float* __restrict__ sup_pos, const float* __restrict__ exh_pos,
        const float* __restrict__ pa, const float* __restrict__ pb, const float* __restrict__ pc,
        const float* __restrict__ slr, const float* __restrict__ srl,
        const float* __restrict__ sdo, const float* __restrict__ sdk,
        const float* __restrict__ elr, const float* __restrict__ erl,
        const float* __restrict__ edo, const float* __restrict__ edk,
        float* __restrict__ slots, float* __restrict__ hist,
        float* __restrict__ stage, int use_hist) {
    LaneConsts L = setup_lane(fan_speed, sup_pos, exh_pos, pa, pb, pc,
                              slr, srl, sdo, sdk, elr, erl, edo, edk);
    const float flow_scale = 2.0f / (500.0f + 1e-6f);
    float flow = L.speed * 2.0f;
    float alpha_base = 0.5f;

#pragma unroll 1
    for (int i = 0; i < NOUTER; ++i) {
        float pfin;
        (void)distribute_lane(flow, L.R2, L.Rl, pfin);
        float sys  = sys_from_p(pfin);
        float res  = fan_pressure(flow, L.rspeed, L.speed2, L.a1000, L.b, L.c) - sys;
        float ares = fabsf(res);

        if (stage) {
            if (L.sub == 0)
                stage[(size_t)i * BATCH + L.elem] = ares;   // plain store, off-chain
        } else {
            float m = ares;
            m = fmaxf(m, dpp_movf<DPP_ROR8>(m));
            m = fmaxf(m, __shfl_xor(m, 16));
            m = fmaxf(m, __shfl_xor(m, 32));
            if (L.lane == 0)
                atomicMax((int*)&slots[i], __float_as_int(m));
        }

        float alpha = fmaxf(alpha_base, 0.05f);
        alpha_base *= 0.95f;
        float fnew = fmaf(alpha * res, flow_scale, flow);
        flow = fminf(fmaxf(fnew, 0.01f), 3.0f);
        if (use_hist && L.sub == 0) hist[(size_t)i * BATCH + L.elem] = flow;
    }
}

// ---------------------------------------------------------------------------
// Phase 1b: block b computes slots[b] = max over stage[b*BATCH .. +BATCH).
// Exact (max order-independent) -> slots bit-identical to atomic path.
// 256 threads x 8 float4 = 8192 floats.
// ---------------------------------------------------------------------------
__global__ __launch_bounds__(256) void phase1b(const float* __restrict__ stage,
                                               float* __restrict__ slots) {
    const float4* src = (const float4*)(stage + (size_t)blockIdx.x * BATCH);
    float m = 0.0f;
#pragma unroll
    for (int q = 0; q < 8; ++q) {            // 2048 float4 total
        float4 v = src[threadIdx.x + 256 * q];
        m = fmaxf(m, fmaxf(fmaxf(v.x, v.y), fmaxf(v.z, v.w)));
    }
#pragma unroll
    for (int off = 32; off; off >>= 1) m = fmaxf(m, __shfl_xor(m, off));
    __shared__ float red[4];
    if ((threadIdx.x & 63) == 0) red[threadIdx.x >> 6] = m;
    __syncthreads();
    if (threadIdx.x == 0)
        slots[blockIdx.x] = fmaxf(fmaxf(red[0], red[1]), fmaxf(red[2], red[3]));
}

// ---------------------------------------------------------------------------
// Phase 1c: single thread runs the stall/done automaton once -> k.
// ---------------------------------------------------------------------------
__global__ void phase1c(const float* __restrict__ slots, int* __restrict__ kout) {
    float prev = INFINITY;
    int stall = 0, k = NOUTER;
    bool done = false;
#pragma unroll 1
    for (int i = 0; i < NOUTER; ++i) {
        float err = slots[i];
        bool stalled = fabsf(err - prev) < 1e-6f;
        stall = stalled ? stall + 1 : 0;
        done = done || (err < 1e-3f) || (stall > 10);
        if (done) { k = i; break; }
        prev = err;
    }
    *kout = k;
}

// ---------------------------------------------------------------------------
// Phase 3: read k, recover flow after k updates, compute outputs.
// ---------------------------------------------------------------------------
template <bool USE_HIST>
__global__ __launch_bounds__(256) void phase3(
        const float* __restrict__ fan_speed,
        const float* __restrict__ sup_pos, const float* __restrict__ exh_pos,
        const float* __restrict__ pa, const float* __restrict__ pb, const float* __restrict__ pc,
        const float* __restrict__ slr, const float* __restrict__ srl,
        const float* __restrict__ sdo, const float* __restrict__ sdk,
        const float* __restrict__ elr, const float* __restrict__ erl,
        const float* __restrict__ edo, const float* __restrict__ edk,
        const float* __restrict__ slots, const int* __restrict__ kin, int use_k,
        const float* __restrict__ hist, float* __restrict__ out) {
    LaneConsts L = setup_lane(fan_speed, sup_pos, exh_pos, pa, pb, pc,
                              slr, srl, sdo, sdk, elr, erl, edo, edk);

    int k;
    if (use_k) {
        k = *kin;                      // uniform scalar load, automaton pre-run
    } else {
        float prev = INFINITY;
        int stall = 0; k = NOUTER;
        bool done = false;
#pragma unroll 1
        for (int i = 0; i < NOUTER; ++i) {
            float err = slots[i];
            bool stalled = fabsf(err - prev) < 1e-6f;
            stall = stalled ? stall + 1 : 0;
            done = done || (err < 1e-3f) || (stall > 10);
            if (done) { k = i; break; }
            prev = err;
        }
    }

    const float flow_scale = 2.0f / (500.0f + 1e-6f);
    float flow;
    if (USE_HIST) {
        flow = (k == 0) ? L.speed * 2.0f : hist[(size_t)(k - 1) * BATCH + L.elem];
    } else {
        flow = L.speed * 2.0f;
        float alpha_base = 0.5f;
#pragma unroll 1
        for (int i = 0; i < k; ++i) {
            float pfin;
            (void)distribute_lane(flow, L.R2, L.Rl, pfin);
            float sys = sys_from_p(pfin);
            float res = fan_pressure(flow, L.rspeed, L.speed2, L.a1000, L.b, L.c) - sys;
            float alpha = fmaxf(alpha_base, 0.05f);
            alpha_base *= 0.95f;
            float fnew = fmaf(alpha * res, flow_scale, flow);
            flow = fminf(fmaxf(fnew, 0.01f), 3.0f);
        }
    }

    flow = fmaxf(flow, 0.0f);
    float fanp = fan_pressure(flow, L.rspeed, L.speed2, L.a1000, L.b, L.c);

    float pfin;
    float ffin = distribute_lane(flow, L.R2, L.Rl, pfin);
    float sys  = sys_from_p(pfin);

    float fr  = flow * (1.0f / (2.0f + 1e-6f));
    float pr  = fanp * (1.0f / (500.0f + 1e-6f));
    float eta = 0.65f * (1.0f - 0.3f * (fr - 1.0f) * (fr - 1.0f)
                              - 0.2f * (pr - 1.0f) * (pr - 1.0f));
    eta = fminf(fmaxf(eta, 0.3f), 0.75f);
    float power = flow * fanp * fast_rcp(eta * 0.9f + 1e-6f);

    float* o = out + (size_t)L.elem * 20;
    if (L.sub == 0) {
        o[0] = flow; o[1] = fanp; o[2] = sys; o[3] = power;
    }
    int net = (L.sub >> 2) & 1;
    int j   = L.sub & 3;
    o[4 + net * 8 + j] = ffin;
    o[8 + net * 8 + j] = pfin;
}

// ---------------------------------------------------------------------------
extern "C" void kernel_launch(void* const* d_in, const int* in_sizes, int n_in,
                              void* d_out, int out_size, void* d_ws, size_t ws_size,
                              hipStream_t stream) {
    const float* fan_speed = (const float*)d_in[0];
    const float* sup_pos   = (const float*)d_in[1];
    const float* exh_pos   = (const float*)d_in[2];
    const float* pa        = (const float*)d_in[3];
    const float* pb        = (const float*)d_in[4];
    const float* pc        = (const float*)d_in[5];
    const float* slr       = (const float*)d_in[6];
    const float* srl       = (const float*)d_in[7];
    const float* sdo       = (const float*)d_in[8];
    const float* sdk       = (const float*)d_in[9];
    const float* elr       = (const float*)d_in[10];
    const float* erl       = (const float*)d_in[11];
    const float* edo       = (const float*)d_in[12];
    const float* edk       = (const float*)d_in[13];

    float* ws    = (float*)d_ws;
    float* slots = ws;                         // 64 floats (also fallback path)
    int*   kptr  = (int*)(ws + 64);            // 1 int
    float* hist  = ws + 128;                   // BATCH*NOUTER floats (1.6 MB)
    float* stage = ws + 128 + BATCH * NOUTER;  // BATCH*NOUTER floats (1.6 MB)

    size_t need_hist  = (size_t)(128 + BATCH * NOUTER) * sizeof(float);
    size_t need_stage = need_hist + (size_t)BATCH * NOUTER * sizeof(float);
    bool use_hist  = ws_size >= need_hist;
    bool use_stage = ws_size >= need_stage;

    dim3 grid(NTHREADS / 256), block(256);

    phase1<<<grid, block, 0, stream>>>(fan_speed, sup_pos, exh_pos, pa, pb, pc,
                                       slr, srl, sdo, sdk, elr, erl, edo, edk,
                                       slots, hist, use_stage ? stage : nullptr,
                                       use_hist ? 1 : 0);
    if (use_stage) {
        phase1b<<<dim3(NOUTER), dim3(256), 0, stream>>>(stage, slots);
        phase1c<<<dim3(1), dim3(1), 0, stream>>>(slots, kptr);
    }

    if (use_hist) {
        phase3<true><<<grid, block, 0, stream>>>(fan_speed, sup_pos, exh_pos, pa, pb, pc,
                                                 slr, srl, sdo, sdk, elr, erl, edo, edk,
                                                 slots, kptr, use_stage ? 1 : 0,
                                                 hist, (float*)d_out);
    } else {
        phase3<false><<<grid, block, 0, stream>>>(fan_speed, sup_pos, exh_pos, pa, pb, pc,
                                                  slr, srl, sdo, sdk, elr, erl, edo, edk,
                                                  slots, kptr, use_stage ? 1 : 0,
                                                  nullptr, (float*)d_out);
    }
}